// Round 11
// baseline (186.985 us; speedup 1.0000x reference)
//
#include <hip/hip_runtime.h>

typedef unsigned short u16;
typedef unsigned int u32;
typedef __attribute__((ext_vector_type(4))) short short4_t;
typedef __attribute__((ext_vector_type(8))) short short8;
typedef __attribute__((ext_vector_type(4))) float f32x4;
typedef __attribute__((ext_vector_type(16))) float f32x16;
typedef __attribute__((ext_vector_type(4))) u32 u32x4;
typedef __attribute__((ext_vector_type(4))) u16 u16x4;

#define DEV __device__ __forceinline__

constexpr int cN = 4096, cD = 256, cF = 128, cH = 8, cDQ = 32;

DEV u16 f2bf(float f){
  union { float f; unsigned u; } v; v.f = f;
  unsigned u = v.u;
  u += 0x7fffu + ((u >> 16) & 1u);   // round-to-nearest-even
  return (u16)(u >> 16);
}
DEV float bf2f(u16 u){
  union { unsigned u; float f; } v; v.u = ((unsigned)u) << 16;
  return v.f;
}
// pack 2 f32 -> u32 of 2 bf16, TRUNCATION (cheap; P in (0,~2], err 2^-8)
DEV u32 pktr(float a, float b){
  return (__float_as_uint(a) >> 16) | (__float_as_uint(b) & 0xffff0000u);
}

// async global->LDS, 16B per lane. LDS dest is wave-uniform base + lane*16.
DEV void gl16(const void* g, void* l){
  __builtin_amdgcn_global_load_lds((const __attribute__((address_space(1))) void*)g,
                                   (__attribute__((address_space(3))) void*)l, 16, 0, 0);
}

// ---------- conversion kernels ----------
__global__ __launch_bounds__(256) void k_conv8(const float* __restrict__ src, u16* __restrict__ dst, int n8){
  int i = blockIdx.x * blockDim.x + threadIdx.x;
  if (i >= n8) return;
  const float4* s4 = (const float4*)src;
  float4 a = s4[2*i], b = s4[2*i+1];
  u16 r[8];
  r[0]=f2bf(a.x); r[1]=f2bf(a.y); r[2]=f2bf(a.z); r[3]=f2bf(a.w);
  r[4]=f2bf(b.x); r[5]=f2bf(b.y); r[6]=f2bf(b.z); r[7]=f2bf(b.w);
  *(short8*)(dst + 8*(size_t)i) = *(short8*)r;
}

// x f32 -> xb bf16 [m][d]  AND  xtT bf16 [d][m] = bf16(x[m][d]*t[m])
__global__ __launch_bounds__(256) void k_convx(const float* __restrict__ x, const float* __restrict__ t,
    u16* __restrict__ xb, u16* __restrict__ xtT){
  int i = blockIdx.x * blockDim.x + threadIdx.x;
  if (i >= cN*cD) return;
  int m = i >> 8, d = i & 255;
  float xv = x[i];
  xb[i] = f2bf(xv);
  xtT[(size_t)d*cN + m] = f2bf(xv * t[m]);
}

// 3 x (B,R,C) f32 -> (3,B,C,R) bf16
__global__ __launch_bounds__(256) void k_tconv3(const float* __restrict__ s0, const float* __restrict__ s1,
    const float* __restrict__ s2, u16* __restrict__ dst, int B, int R, int C){
  int i = blockIdx.x * blockDim.x + threadIdx.x;
  int tot = B*R*C;
  if (i >= 3*tot) return;
  int w = i / tot, rem0 = i - w*tot;
  const float* src = (w == 0) ? s0 : (w == 1) ? s1 : s2;
  int rc = R*C;
  int b = rem0 / rc, rem = rem0 - b*rc, r = rem / C, c = rem - r*C;
  dst[(size_t)w*B*rc + (size_t)b*rc + (size_t)c*R + r] = f2bf(src[rem0]);
}

// (B,R,C) f32 -> (B,C,R) bf16
__global__ __launch_bounds__(256) void k_tconv(const float* __restrict__ src, u16* __restrict__ dst, int B, int R, int C){
  int i = blockIdx.x * blockDim.x + threadIdx.x;
  if (i >= B*R*C) return;
  int rc = R*C;
  int b = i / rc, rem = i - b*rc, r = rem / C, c = rem - r*C;
  dst[(size_t)b*rc + (size_t)c*R + r] = f2bf(src[i]);
}

// ---------- shared GEMM pieces (128x128 tile, BK=64, 4 waves 2x2) ----------
DEV void stage_gl(const u16* __restrict__ src, int ld, u16* lds, int wave, int lane){
  int sub = lane >> 3, ch = lane & 7;
#pragma unroll
  for (int i = 0; i < 4; ++i){
    int rowbase = wave*32 + i*8;
    const u16* g = src + (size_t)(rowbase + sub)*ld + ((ch ^ sub) * 8);
    gl16(g, lds + rowbase*64);
  }
}

DEV void mma_tile(const u16* ldsA, const u16* ldsB, f32x4 acc[4][4], int wr, int wc, int g, int ln){
#pragma unroll
  for (int kt = 0; kt < 2; ++kt){
    short8 a[4], b[4];
#pragma unroll
    for (int ti = 0; ti < 4; ++ti){
      int row = wr*64 + ti*16 + ln;
      a[ti] = *(const short8*)(ldsA + row*64 + (((kt*4 + g) ^ (row & 7)) * 8));
    }
#pragma unroll
    for (int tj = 0; tj < 4; ++tj){
      int row = wc*64 + tj*16 + ln;
      b[tj] = *(const short8*)(ldsB + row*64 + (((kt*4 + g) ^ (row & 7)) * 8));
    }
#pragma unroll
    for (int ti = 0; ti < 4; ++ti)
#pragma unroll
      for (int tj = 0; tj < 4; ++tj)
        acc[ti][tj] = __builtin_amdgcn_mfma_f32_16x16x32_bf16(a[ti], b[tj], acc[ti][tj], 0, 0, 0);
  }
}

// ---------- K_Y: y = adj @ (x*t), K-split x8 ----------
__global__ __launch_bounds__(256) void k_ygemm(const u16* __restrict__ adjb, const u16* __restrict__ xtT,
    float* __restrict__ ypart){
  __shared__ __align__(16) u16 ldsA[8192], ldsB[8192];
  int bid = blockIdx.x;
  int ks = bid & 7, nt = (bid >> 3) & 1, mt = bid >> 4;
  const u16* A  = adjb + (size_t)mt * 128 * cN + ks * 512;
  const u16* Bt = xtT + (size_t)nt * 128 * cN + ks * 512;
  int tid = threadIdx.x, wave = tid >> 6, lane = tid & 63;
  int wr = wave >> 1, wc = wave & 1, g = lane >> 4, ln = lane & 15;
  f32x4 acc[4][4];
#pragma unroll
  for (int i=0;i<4;i++)
#pragma unroll
    for (int j=0;j<4;j++) acc[i][j] = f32x4{0.f,0.f,0.f,0.f};
  for (int k0 = 0; k0 < 512; k0 += 64){
    stage_gl(A + k0, cN, ldsA, wave, lane);
    stage_gl(Bt + k0, cN, ldsB, wave, lane);
    __syncthreads();
    mma_tile(ldsA, ldsB, acc, wr, wc, g, ln);
    __syncthreads();
  }
  float* yp = ypart + (size_t)ks * (cN * cD);
#pragma unroll
  for (int ti=0;ti<4;ti++)
#pragma unroll
    for (int tj=0;tj<4;tj++)
#pragma unroll
      for (int r=0;r<4;r++){
        int n = mt*128 + wr*64 + ti*16 + g*4 + r;
        int d = nt*128 + wc*64 + tj*16 + ln;
        yp[(size_t)n*cD + d] = acc[ti][tj][r];
      }
}

// ---------- K_YC: combine 8 K-splits -> yb = bf16(y), ybc = bf16(y + x*t) ----------
__global__ __launch_bounds__(256) void k_ycomb(const float* __restrict__ ypart, const float* __restrict__ x,
    const float* __restrict__ t, u16* __restrict__ yb, u16* __restrict__ ybc){
  int j = blockIdx.x * blockDim.x + threadIdx.x;   // over cN*cD/4
  if (j >= cN*cD/4) return;
  int idx = j * 4;
  int n = idx >> 8;
  float4 s = {0.f,0.f,0.f,0.f};
#pragma unroll
  for (int ks = 0; ks < 8; ++ks){
    float4 p = *(const float4*)(ypart + (size_t)ks*(cN*cD) + idx);
    s.x += p.x; s.y += p.y; s.z += p.z; s.w += p.w;
  }
  float tv = t[n];
  float4 xv = *(const float4*)(x + idx);
  u16x4 a = { f2bf(s.x), f2bf(s.y), f2bf(s.z), f2bf(s.w) };
  u16x4 b = { f2bf(s.x + xv.x*tv), f2bf(s.y + xv.y*tv), f2bf(s.z + xv.z*tv), f2bf(s.w + xv.w*tv) };
  *(u16x4*)(yb + idx) = a;
  *(u16x4*)(ybc + idx) = b;
}

// ---------- K1: h_x / h_n / h_c  (A @ W, 24 channels, K=256) ----------
__global__ __launch_bounds__(256) void k_xw2(const u16* __restrict__ xb, const u16* __restrict__ yb,
    const u16* __restrict__ ybc, const u16* __restrict__ w3t,
    const float* __restrict__ bself, const float* __restrict__ bn, const float* __restrict__ bc,
    u16* __restrict__ hx, u16* __restrict__ hn, u16* __restrict__ hc){
  __shared__ __align__(16) u16 ldsA[8192], ldsB[8192];
  int bid = blockIdx.x;
  int mt = bid & 31, c = bid >> 5;
  int set = c >> 3, h = c & 7;
  const u16* Asrc = (set == 0) ? xb : (set == 1) ? yb : ybc;
  const u16* A  = Asrc + (size_t)mt * 128 * cD;
  const u16* Bt = w3t + (size_t)c * cF * cD;
  const float* bias = (set == 0) ? bself : (set == 1) ? bn : bc;
  u16* dst = (set == 0) ? hx : (set == 1) ? hn : hc;
  int tid = threadIdx.x, wave = tid >> 6, lane = tid & 63;
  int wr = wave >> 1, wc = wave & 1, g = lane >> 4, ln = lane & 15;
  f32x4 acc[4][4];
#pragma unroll
  for (int i=0;i<4;i++)
#pragma unroll
    for (int j=0;j<4;j++) acc[i][j] = f32x4{0.f,0.f,0.f,0.f};
  for (int k0 = 0; k0 < cD; k0 += 64){
    stage_gl(A + k0, cD, ldsA, wave, lane);
    stage_gl(Bt + k0, cD, ldsB, wave, lane);
    __syncthreads();
    mma_tile(ldsA, ldsB, acc, wr, wc, g, ln);
    __syncthreads();
  }
#pragma unroll
  for (int ti=0;ti<4;ti++)
#pragma unroll
    for (int tj=0;tj<4;tj++)
#pragma unroll
      for (int r=0;r<4;r++){
        int n = mt*128 + wr*64 + ti*16 + g*4 + r;
        int f = wc*64 + tj*16 + ln;
        float v = fmaxf(acc[ti][tj][r] + bias[h*cF + f], 0.f);
        dst[((size_t)h*cN + n)*cF + f] = f2bf(v);
      }
}

// ---------- K3: q/k/v (24 channels, Nc=32) ----------
__global__ __launch_bounds__(256) void k_qkv(const u16* __restrict__ hx, const u16* __restrict__ hn,
    const u16* __restrict__ hc, const u16* __restrict__ wqkvt,
    const float* __restrict__ bq, const float* __restrict__ bk, const float* __restrict__ bv,
    u16* __restrict__ qb, u16* __restrict__ kb, u16* __restrict__ vt){
  __shared__ __align__(16) u16 ldsA[8192], ldsB[2048];
  int bid = blockIdx.x;
  int mt = bid & 31, c = bid >> 5;
  int set = c >> 3, h = c & 7;
  const u16* A = (set == 0 ? hx : (set == 1 ? hn : hc)) + (size_t)h * cN * cF + (size_t)mt * 128 * cF;
  const u16* Bt = wqkvt + (size_t)c * cDQ * cF;
  int tid = threadIdx.x, w = tid >> 6, lane = tid & 63;
  int g = lane >> 4, ln = lane & 15;
  f32x4 acc[2][2];
#pragma unroll
  for (int i=0;i<2;i++)
#pragma unroll
    for (int j=0;j<2;j++) acc[i][j] = f32x4{0.f,0.f,0.f,0.f};
  for (int k0 = 0; k0 < cF; k0 += 64){
    stage_gl(A + k0, cF, ldsA, w, lane);
    { int row = tid >> 3, cb = tid & 7;   // 32 rows x 8 chunks (reg-staged, small)
      *(short8*)(ldsB + row*64 + ((cb ^ (row & 7)) * 8)) = *(const short8*)(Bt + (size_t)row*cF + k0 + cb*8); }
    __syncthreads();
#pragma unroll
    for (int kt = 0; kt < 2; ++kt){
      short8 a[2], b[2];
#pragma unroll
      for (int ti=0;ti<2;ti++){
        int row = w*32 + ti*16 + ln;
        a[ti] = *(const short8*)(ldsA + row*64 + (((kt*4 + g) ^ (row & 7)) * 8));
      }
#pragma unroll
      for (int tj=0;tj<2;tj++){
        int row = tj*16 + ln;
        b[tj] = *(const short8*)(ldsB + row*64 + (((kt*4 + g) ^ (row & 7)) * 8));
      }
#pragma unroll
      for (int ti=0;ti<2;ti++)
#pragma unroll
        for (int tj=0;tj<2;tj++)
          acc[ti][tj] = __builtin_amdgcn_mfma_f32_16x16x32_bf16(a[ti], b[tj], acc[ti][tj], 0, 0, 0);
    }
    __syncthreads();
  }
  // fold 1/sqrt(DQ) * log2(e) into q so attention softmax runs in exp2 domain
  const float qscale = 0.17677669529663687f * 1.4426950408889634f;
#pragma unroll
  for (int ti=0;ti<2;ti++)
#pragma unroll
    for (int tj=0;tj<2;tj++)
#pragma unroll
      for (int r=0;r<4;r++){
        int n = mt*128 + w*32 + ti*16 + g*4 + r;
        int d = tj*16 + ln;
        float v = acc[ti][tj][r];
        if (set == 0){
          v = (v + bq[h*cDQ + d]) * qscale;
          qb[((size_t)h*cN + n)*cDQ + d] = f2bf(v);
        } else if (set == 1){
          v += bk[h*cDQ + d];
          kb[((size_t)h*cN + n)*cDQ + d] = f2bf(v);
        } else {
          v += bv[h*cDQ + d];
          vt[(size_t)h*cDQ*cN + (size_t)d*cN + n] = f2bf(v);
        }
      }
}

// ---------- K4: flash attention, swapped-QK^T 32x32, shuffle-free PV ----------
// Max-free softmax (|S_log2| small by construction). KV-split x8.
// PV trick: MFMA only needs A and B to share the same (hi,j)->key bijection.
// P's natural layout f(hi,j) = (j&3)+8*(j>>2)+4*hi is bijective, so we pack P
// in-order (no cross-lane ops) and load V^T at matching addresses (4x short4).
__global__ __launch_bounds__(256) void k_attn(const u16* __restrict__ qb, const u16* __restrict__ kb,
    const u16* __restrict__ vt, float* __restrict__ opart, float* __restrict__ lpart){
  int bid = blockIdx.x;
  int h = bid & 7, s = (bid >> 3) & 7, qt = bid >> 6;
  int tid = threadIdx.x, w = tid >> 6, lane = tid & 63;
  int lq = lane & 31, hi = lane >> 5;
  int q0 = qt*128 + w*32;
  const u16* qh = qb + (size_t)h * cN * cDQ;
  const u16* kh = kb + (size_t)h * cN * cDQ;
  const u16* vh = vt + (size_t)h * cDQ * cN;
  short8 fq0 = *(const short8*)(qh + (size_t)(q0 + lq)*cDQ + hi*8);
  short8 fq1 = *(const short8*)(qh + (size_t)(q0 + lq)*cDQ + 16 + hi*8);
  f32x16 o;
#pragma unroll
  for (int r=0;r<16;r++) o[r] = 0.f;
  float l_loc = 0.f;
  const u16* vrow = vh + (size_t)lq * cN;
  for (int kc = 0; kc < 16; ++kc){
    int kbase = s*512 + kc*32;
    short8 fk0 = *(const short8*)(kh + (size_t)(kbase + lq)*cDQ + hi*8);
    short8 fk1 = *(const short8*)(kh + (size_t)(kbase + lq)*cDQ + 16 + hi*8);
    f32x16 sa;
#pragma unroll
    for (int r=0;r<16;r++) sa[r] = 0.f;
    sa = __builtin_amdgcn_mfma_f32_32x32x16_bf16(fk0, fq0, sa, 0, 0, 0);
    sa = __builtin_amdgcn_mfma_f32_32x32x16_bf16(fk1, fq1, sa, 0, 0, 0);
    // p = exp2(S) directly (no max). In-lane sum only; cross-half ONCE after loop.
    float pf[16];
#pragma unroll
    for (int r=0;r<16;r++) pf[r] = __builtin_exp2f(sa[r]);
    float s01 = (pf[0]+pf[1]) + (pf[2]+pf[3]);
    float s23 = (pf[4]+pf[5]) + (pf[6]+pf[7]);
    float s45 = (pf[8]+pf[9]) + (pf[10]+pf[11]);
    float s67 = (pf[12]+pf[13]) + (pf[14]+pf[15]);
    l_loc += (s01 + s23) + (s45 + s67);
    // pack P in NATURAL order: pa1 elem 2i,2i+1 = pf[2i],pf[2i+1] (keys f(hi,j))
    union { u32x4 u; short8 s8; } pa1, pa2;
    pa1.u = u32x4{ pktr(pf[0], pf[1]),  pktr(pf[2], pf[3]),
                   pktr(pf[4], pf[5]),  pktr(pf[6], pf[7]) };
    pa2.u = u32x4{ pktr(pf[8], pf[9]),  pktr(pf[10], pf[11]),
                   pktr(pf[12], pf[13]), pktr(pf[14], pf[15]) };
    // V^T loads matching f: element j of fv0 = V^T[lq][kbase + (j&3)+8*(j>>2)+4*hi]
    union { short4_t h4[2]; short8 s8; } fv0, fv1;
    fv0.h4[0] = *(const short4_t*)(vrow + kbase + 4*hi);
    fv0.h4[1] = *(const short4_t*)(vrow + kbase + 8 + 4*hi);
    fv1.h4[0] = *(const short4_t*)(vrow + kbase + 16 + 4*hi);
    fv1.h4[1] = *(const short4_t*)(vrow + kbase + 24 + 4*hi);
    // O^T[d][q] += V^T[d][k] * P[k][q]  (shared bijection per 16-k block)
    o = __builtin_amdgcn_mfma_f32_32x32x16_bf16(fv0.s8, pa1.s8, o, 0, 0, 0);
    o = __builtin_amdgcn_mfma_f32_32x32x16_bf16(fv1.s8, pa2.s8, o, 0, 0, 0);
  }
  float l_ = l_loc + __shfl_xor(l_loc, 32);
  // o[r] = O[q = q0+lq][d = (r&3)+8*(r>>2)+4*hi]
  size_t ob_base = ((size_t)(s*cH + h) * cN) * cDQ;
  float* orow = opart + ob_base + (size_t)(q0 + lq)*cDQ;
#pragma unroll
  for (int blk=0; blk<4; ++blk){
    f32x4 v4 = { o[blk*4+0], o[blk*4+1], o[blk*4+2], o[blk*4+3] };
    *(f32x4*)(orow + blk*8 + 4*hi) = v4;
  }
  if (lane < 32){
    lpart[(size_t)(s*cH + h) * cN + q0 + lane] = l_;
  }
}

// ---------- K4b: combine the 8 KV splits (max-free: weights all 1) ----------
__global__ __launch_bounds__(256) void k_comb(const float* __restrict__ opart,
    const float* __restrict__ lpart, u16* __restrict__ ob){
  int i = blockIdx.x * blockDim.x + threadIdx.x;   // over 8*4096*8
  int hq = i >> 3, dd = (i & 7) * 4;
  int h = hq >> 12, q = hq & 4095;
  float l = 0.f;
#pragma unroll
  for (int s = 0; s < 8; ++s) l += lpart[s*32768 + hq];
  float inv = 1.f / l;
  size_t base = (size_t)hq * cDQ + dd;
  float4 acc = {0.f,0.f,0.f,0.f};
#pragma unroll
  for (int s = 0; s < 8; ++s){
    float4 p = *(const float4*)(opart + (size_t)s*1048576 + base);
    acc.x += p.x; acc.y += p.y; acc.z += p.z; acc.w += p.w;
  }
  u16* dst = ob + (size_t)q * (cH*cDQ) + h*cDQ + dd;
  dst[0] = f2bf(acc.x*inv); dst[1] = f2bf(acc.y*inv);
  dst[2] = f2bf(acc.z*inv); dst[3] = f2bf(acc.w*inv);
}

// ---------- K5: final projection o @ Wo + bo ----------
__global__ __launch_bounds__(256) void k_out(const u16* __restrict__ ob, const u16* __restrict__ wot,
    const float* __restrict__ bo, float* __restrict__ out){
  __shared__ __align__(16) u16 ldsA[8192], ldsB[8192];
  int mt = blockIdx.x;
  const u16* A = ob + (size_t)mt * 128 * 256;
  const u16* Bt = wot;
  int tid = threadIdx.x, wave = tid >> 6, lane = tid & 63;
  int wr = wave >> 1, wc = wave & 1, g = lane >> 4, ln = lane & 15;
  f32x4 acc[4][4];
#pragma unroll
  for (int i=0;i<4;i++)
#pragma unroll
    for (int j=0;j<4;j++) acc[i][j] = f32x4{0.f,0.f,0.f,0.f};
  for (int k0 = 0; k0 < 256; k0 += 64){
    stage_gl(A + k0, 256, ldsA, wave, lane);
    stage_gl(Bt + k0, 256, ldsB, wave, lane);
    __syncthreads();
    mma_tile(ldsA, ldsB, acc, wr, wc, g, ln);
    __syncthreads();
  }
#pragma unroll
  for (int ti=0;ti<4;ti++)
#pragma unroll
    for (int tj=0;tj<4;tj++)
#pragma unroll
      for (int r=0;r<4;r++){
        int n = mt*128 + wr*64 + ti*16 + g*4 + r;
        int f = wc*64 + tj*16 + ln;
        out[(size_t)n*cF + f] = acc[ti][tj][r] + bo[f];
      }
}

extern "C" void kernel_launch(void* const* d_in, const int* in_sizes, int n_in,
                              void* d_out, int out_size, void* d_ws, size_t ws_size,
                              hipStream_t stream){
  const float* adj  = (const float*)d_in[0];
  const float* x    = (const float*)d_in[1];
  const float* tvec = (const float*)d_in[2];
  // d_in[3] = PNum (unused)
  const float* Wself= (const float*)d_in[4];
  const float* bself= (const float*)d_in[5];
  const float* Wn   = (const float*)d_in[6];
  const float* bn   = (const float*)d_in[7];
  const float* Wc   = (const float*)d_in[8];
  const float* bc   = (const float*)d_in[9];
  const float* Wq   = (const float*)d_in[10];
  const float* bq   = (const float*)d_in[11];
  const float* Wk   = (const float*)d_in[12];
  const float* bk   = (const float*)d_in[13];
  const float* Wv   = (const float*)d_in[14];
  const float* bv   = (const float*)d_in[15];
  const float* Wo   = (const float*)d_in[16];
  const float* bo   = (const float*)d_in[17];
  float* out = (float*)d_out;

  char* ws = (char*)d_ws;
  u16* adjb = (u16*)(ws);              // 33,554,432 B (dead after k_ygemm)
  u16* xb   = (u16*)(ws + 33554432);   // 4096*256*2
  u16* xtT  = (u16*)(ws + 35651584);   // 256*4096*2 (x*t transposed)
  u16* w3t  = (u16*)(ws + 37748736);   // [3][8][128][256]*2 = 1,572,864
  u16* wqkvt= (u16*)(ws + 39321600);   // [3][8][32][128]*2 = 196,608
  u16* wot  = (u16*)(ws + 39518208);   // [128][256]*2 = 65,536
  u16* yb   = (u16*)(ws + 39583744);   // 4096*256*2
  u16* ybc  = (u16*)(ws + 41680896);   // 4096*256*2
  u16* hx   = (u16*)(ws + 43778048);   // [8][4096][128]*2 = 8,388,608
  u16* hn   = (u16*)(ws + 52166656);   // 8,388,608
  u16* hc   = (u16*)(ws + 60555264);   // 8,388,608
  u16* qb   = (u16*)(ws + 68943872);   // 2,097,152
  u16* kb   = (u16*)(ws + 71041024);   // 2,097,152
  u16* vt   = (u16*)(ws + 73138176);   // 2,097,152
  u16* ob   = (u16*)(ws + 75235328);   // 2,097,152
  // y partials alias hx..ob region (dead until k_ycomb finishes)
  float* ypart = (float*)(ws + 43778048);   // [8][4096][256] f32 = 33,554,432
  // attention partials: opart aliases adjb exactly (dead after k_ygemm)
  float* opart = (float*)(ws);              // [8][8][4096][32] f32 = 33,554,432
  float* lpart = (float*)(ws + 77332480);   // [8][8][4096] f32 = 1,048,576  (total 78,381,056)

  k_conv8<<<8192, 256, 0, stream>>>(adj, adjb, 2097152);
  k_convx<<<4096, 256, 0, stream>>>(x, tvec, xb, xtT);
  k_tconv3<<<3072, 256, 0, stream>>>(Wself, Wn, Wc, w3t, 8, 256, 128);
  k_tconv3<<<384, 256, 0, stream>>>(Wq, Wk, Wv, wqkvt, 8, 128, 32);
  k_tconv<<<128, 256, 0, stream>>>(Wo, wot, 1, 256, 128);
  k_ygemm<<<512, 256, 0, stream>>>(adjb, xtT, ypart);
  k_ycomb<<<1024, 256, 0, stream>>>(ypart, x, tvec, yb, ybc);
  k_xw2<<<768, 256, 0, stream>>>(xb, yb, ybc, w3t, bself, bn, bc, hx, hn, hc);
  k_qkv<<<768, 256, 0, stream>>>(hx, hn, hc, wqkvt, bq, bk, bv, qb, kb, vt);
  k_attn<<<2048, 256, 0, stream>>>(qb, kb, vt, opart, lpart);
  k_comb<<<1024, 256, 0, stream>>>(opart, lpart, ob);
  k_out<<<32, 256, 0, stream>>>(ob, wot, bo, out);
}

// Round 12
// 148.919 us; speedup vs baseline: 1.2556x; 1.2556x over previous
//
#include <hip/hip_runtime.h>

typedef unsigned short u16;
typedef unsigned int u32;
typedef __attribute__((ext_vector_type(8))) short short8;
typedef __attribute__((ext_vector_type(4))) float f32x4;
typedef __attribute__((ext_vector_type(16))) float f32x16;
typedef __attribute__((ext_vector_type(4))) u32 u32x4;
typedef __attribute__((ext_vector_type(4))) u16 u16x4;

#define DEV __device__ __forceinline__

constexpr int cN = 4096, cD = 256, cF = 128, cH = 8, cDQ = 32;

DEV u16 f2bf(float f){
  union { float f; unsigned u; } v; v.f = f;
  unsigned u = v.u;
  u += 0x7fffu + ((u >> 16) & 1u);   // round-to-nearest-even
  return (u16)(u >> 16);
}
DEV float bf2f(u16 u){
  union { unsigned u; float f; } v; v.u = ((unsigned)u) << 16;
  return v.f;
}
// pack 2 f32 -> u32 of 2 bf16, TRUNCATION (cheap; P in (0,~2], err 2^-8)
DEV u32 pktr(float a, float b){
  return (__float_as_uint(a) >> 16) | (__float_as_uint(b) & 0xffff0000u);
}

// async global->LDS, 16B per lane. LDS dest is wave-uniform base + lane*16.
DEV void gl16(const void* g, void* l){
  __builtin_amdgcn_global_load_lds((const __attribute__((address_space(1))) void*)g,
                                   (__attribute__((address_space(3))) void*)l, 16, 0, 0);
}

// ---------- conversion kernels ----------
__global__ __launch_bounds__(256) void k_conv8(const float* __restrict__ src, u16* __restrict__ dst, int n8){
  int i = blockIdx.x * blockDim.x + threadIdx.x;
  if (i >= n8) return;
  const float4* s4 = (const float4*)src;
  float4 a = s4[2*i], b = s4[2*i+1];
  u16 r[8];
  r[0]=f2bf(a.x); r[1]=f2bf(a.y); r[2]=f2bf(a.z); r[3]=f2bf(a.w);
  r[4]=f2bf(b.x); r[5]=f2bf(b.y); r[6]=f2bf(b.z); r[7]=f2bf(b.w);
  *(short8*)(dst + 8*(size_t)i) = *(short8*)r;
}

// x f32 -> xb bf16 [m][d]  AND  xtT bf16 [d][m] = bf16(x[m][d]*t[m])
__global__ __launch_bounds__(256) void k_convx(const float* __restrict__ x, const float* __restrict__ t,
    u16* __restrict__ xb, u16* __restrict__ xtT){
  int i = blockIdx.x * blockDim.x + threadIdx.x;
  if (i >= cN*cD) return;
  int m = i >> 8, d = i & 255;
  float xv = x[i];
  xb[i] = f2bf(xv);
  xtT[(size_t)d*cN + m] = f2bf(xv * t[m]);
}

// 3 x (B,R,C) f32 -> (3,B,C,R) bf16
__global__ __launch_bounds__(256) void k_tconv3(const float* __restrict__ s0, const float* __restrict__ s1,
    const float* __restrict__ s2, u16* __restrict__ dst, int B, int R, int C){
  int i = blockIdx.x * blockDim.x + threadIdx.x;
  int tot = B*R*C;
  if (i >= 3*tot) return;
  int w = i / tot, rem0 = i - w*tot;
  const float* src = (w == 0) ? s0 : (w == 1) ? s1 : s2;
  int rc = R*C;
  int b = rem0 / rc, rem = rem0 - b*rc, r = rem / C, c = rem - r*C;
  dst[(size_t)w*B*rc + (size_t)b*rc + (size_t)c*R + r] = f2bf(src[rem0]);
}

// (B,R,C) f32 -> (B,C,R) bf16
__global__ __launch_bounds__(256) void k_tconv(const float* __restrict__ src, u16* __restrict__ dst, int B, int R, int C){
  int i = blockIdx.x * blockDim.x + threadIdx.x;
  if (i >= B*R*C) return;
  int rc = R*C;
  int b = i / rc, rem = i - b*rc, r = rem / C, c = rem - r*C;
  dst[(size_t)b*rc + (size_t)c*R + r] = f2bf(src[i]);
}

// ---------- shared GEMM pieces (128x128 tile, BK=64, 4 waves 2x2) ----------
DEV void stage_gl(const u16* __restrict__ src, int ld, u16* lds, int wave, int lane){
  int sub = lane >> 3, ch = lane & 7;
#pragma unroll
  for (int i = 0; i < 4; ++i){
    int rowbase = wave*32 + i*8;
    const u16* g = src + (size_t)(rowbase + sub)*ld + ((ch ^ sub) * 8);
    gl16(g, lds + rowbase*64);
  }
}

DEV void mma_tile(const u16* ldsA, const u16* ldsB, f32x4 acc[4][4], int wr, int wc, int g, int ln){
#pragma unroll
  for (int kt = 0; kt < 2; ++kt){
    short8 a[4], b[4];
#pragma unroll
    for (int ti = 0; ti < 4; ++ti){
      int row = wr*64 + ti*16 + ln;
      a[ti] = *(const short8*)(ldsA + row*64 + (((kt*4 + g) ^ (row & 7)) * 8));
    }
#pragma unroll
    for (int tj = 0; tj < 4; ++tj){
      int row = wc*64 + tj*16 + ln;
      b[tj] = *(const short8*)(ldsB + row*64 + (((kt*4 + g) ^ (row & 7)) * 8));
    }
#pragma unroll
    for (int ti = 0; ti < 4; ++ti)
#pragma unroll
      for (int tj = 0; tj < 4; ++tj)
        acc[ti][tj] = __builtin_amdgcn_mfma_f32_16x16x32_bf16(a[ti], b[tj], acc[ti][tj], 0, 0, 0);
  }
}

// ---------- K_Y: y = adj @ (x*t), K-split x8 ----------
__global__ __launch_bounds__(256) void k_ygemm(const u16* __restrict__ adjb, const u16* __restrict__ xtT,
    float* __restrict__ ypart){
  __shared__ __align__(16) u16 ldsA[8192], ldsB[8192];
  int bid = blockIdx.x;
  int ks = bid & 7, nt = (bid >> 3) & 1, mt = bid >> 4;
  const u16* A  = adjb + (size_t)mt * 128 * cN + ks * 512;
  const u16* Bt = xtT + (size_t)nt * 128 * cN + ks * 512;
  int tid = threadIdx.x, wave = tid >> 6, lane = tid & 63;
  int wr = wave >> 1, wc = wave & 1, g = lane >> 4, ln = lane & 15;
  f32x4 acc[4][4];
#pragma unroll
  for (int i=0;i<4;i++)
#pragma unroll
    for (int j=0;j<4;j++) acc[i][j] = f32x4{0.f,0.f,0.f,0.f};
  for (int k0 = 0; k0 < 512; k0 += 64){
    stage_gl(A + k0, cN, ldsA, wave, lane);
    stage_gl(Bt + k0, cN, ldsB, wave, lane);
    __syncthreads();
    mma_tile(ldsA, ldsB, acc, wr, wc, g, ln);
    __syncthreads();
  }
  float* yp = ypart + (size_t)ks * (cN * cD);
#pragma unroll
  for (int ti=0;ti<4;ti++)
#pragma unroll
    for (int tj=0;tj<4;tj++)
#pragma unroll
      for (int r=0;r<4;r++){
        int n = mt*128 + wr*64 + ti*16 + g*4 + r;
        int d = nt*128 + wc*64 + tj*16 + ln;
        yp[(size_t)n*cD + d] = acc[ti][tj][r];
      }
}

// ---------- K_YC: combine 8 K-splits -> yb = bf16(y), ybc = bf16(y + x*t) ----------
__global__ __launch_bounds__(256) void k_ycomb(const float* __restrict__ ypart, const float* __restrict__ x,
    const float* __restrict__ t, u16* __restrict__ yb, u16* __restrict__ ybc){
  int j = blockIdx.x * blockDim.x + threadIdx.x;   // over cN*cD/4
  if (j >= cN*cD/4) return;
  int idx = j * 4;
  int n = idx >> 8;
  float4 s = {0.f,0.f,0.f,0.f};
#pragma unroll
  for (int ks = 0; ks < 8; ++ks){
    float4 p = *(const float4*)(ypart + (size_t)ks*(cN*cD) + idx);
    s.x += p.x; s.y += p.y; s.z += p.z; s.w += p.w;
  }
  float tv = t[n];
  float4 xv = *(const float4*)(x + idx);
  u16x4 a = { f2bf(s.x), f2bf(s.y), f2bf(s.z), f2bf(s.w) };
  u16x4 b = { f2bf(s.x + xv.x*tv), f2bf(s.y + xv.y*tv), f2bf(s.z + xv.z*tv), f2bf(s.w + xv.w*tv) };
  *(u16x4*)(yb + idx) = a;
  *(u16x4*)(ybc + idx) = b;
}

// ---------- K1: h_x / h_n / h_c  (A @ W, 24 channels, K=256) ----------
__global__ __launch_bounds__(256) void k_xw2(const u16* __restrict__ xb, const u16* __restrict__ yb,
    const u16* __restrict__ ybc, const u16* __restrict__ w3t,
    const float* __restrict__ bself, const float* __restrict__ bn, const float* __restrict__ bc,
    u16* __restrict__ hx, u16* __restrict__ hn, u16* __restrict__ hc){
  __shared__ __align__(16) u16 ldsA[8192], ldsB[8192];
  int bid = blockIdx.x;
  int mt = bid & 31, c = bid >> 5;
  int set = c >> 3, h = c & 7;
  const u16* Asrc = (set == 0) ? xb : (set == 1) ? yb : ybc;
  const u16* A  = Asrc + (size_t)mt * 128 * cD;
  const u16* Bt = w3t + (size_t)c * cF * cD;
  const float* bias = (set == 0) ? bself : (set == 1) ? bn : bc;
  u16* dst = (set == 0) ? hx : (set == 1) ? hn : hc;
  int tid = threadIdx.x, wave = tid >> 6, lane = tid & 63;
  int wr = wave >> 1, wc = wave & 1, g = lane >> 4, ln = lane & 15;
  f32x4 acc[4][4];
#pragma unroll
  for (int i=0;i<4;i++)
#pragma unroll
    for (int j=0;j<4;j++) acc[i][j] = f32x4{0.f,0.f,0.f,0.f};
  for (int k0 = 0; k0 < cD; k0 += 64){
    stage_gl(A + k0, cD, ldsA, wave, lane);
    stage_gl(Bt + k0, cD, ldsB, wave, lane);
    __syncthreads();
    mma_tile(ldsA, ldsB, acc, wr, wc, g, ln);
    __syncthreads();
  }
#pragma unroll
  for (int ti=0;ti<4;ti++)
#pragma unroll
    for (int tj=0;tj<4;tj++)
#pragma unroll
      for (int r=0;r<4;r++){
        int n = mt*128 + wr*64 + ti*16 + g*4 + r;
        int f = wc*64 + tj*16 + ln;
        float v = fmaxf(acc[ti][tj][r] + bias[h*cF + f], 0.f);
        dst[((size_t)h*cN + n)*cF + f] = f2bf(v);
      }
}

// ---------- K3: q/k/v (24 channels, Nc=32) ----------
__global__ __launch_bounds__(256) void k_qkv(const u16* __restrict__ hx, const u16* __restrict__ hn,
    const u16* __restrict__ hc, const u16* __restrict__ wqkvt,
    const float* __restrict__ bq, const float* __restrict__ bk, const float* __restrict__ bv,
    u16* __restrict__ qb, u16* __restrict__ kb, u16* __restrict__ vt){
  __shared__ __align__(16) u16 ldsA[8192], ldsB[2048];
  int bid = blockIdx.x;
  int mt = bid & 31, c = bid >> 5;
  int set = c >> 3, h = c & 7;
  const u16* A = (set == 0 ? hx : (set == 1 ? hn : hc)) + (size_t)h * cN * cF + (size_t)mt * 128 * cF;
  const u16* Bt = wqkvt + (size_t)c * cDQ * cF;
  int tid = threadIdx.x, w = tid >> 6, lane = tid & 63;
  int g = lane >> 4, ln = lane & 15;
  f32x4 acc[2][2];
#pragma unroll
  for (int i=0;i<2;i++)
#pragma unroll
    for (int j=0;j<2;j++) acc[i][j] = f32x4{0.f,0.f,0.f,0.f};
  for (int k0 = 0; k0 < cF; k0 += 64){
    stage_gl(A + k0, cF, ldsA, w, lane);
    { int row = tid >> 3, cb = tid & 7;   // 32 rows x 8 chunks (reg-staged, small)
      *(short8*)(ldsB + row*64 + ((cb ^ (row & 7)) * 8)) = *(const short8*)(Bt + (size_t)row*cF + k0 + cb*8); }
    __syncthreads();
#pragma unroll
    for (int kt = 0; kt < 2; ++kt){
      short8 a[2], b[2];
#pragma unroll
      for (int ti=0;ti<2;ti++){
        int row = w*32 + ti*16 + ln;
        a[ti] = *(const short8*)(ldsA + row*64 + (((kt*4 + g) ^ (row & 7)) * 8));
      }
#pragma unroll
      for (int tj=0;tj<2;tj++){
        int row = tj*16 + ln;
        b[tj] = *(const short8*)(ldsB + row*64 + (((kt*4 + g) ^ (row & 7)) * 8));
      }
#pragma unroll
      for (int ti=0;ti<2;ti++)
#pragma unroll
        for (int tj=0;tj<2;tj++)
          acc[ti][tj] = __builtin_amdgcn_mfma_f32_16x16x32_bf16(a[ti], b[tj], acc[ti][tj], 0, 0, 0);
    }
    __syncthreads();
  }
  // fold 1/sqrt(DQ) * log2(e) into q so attention softmax runs in exp2 domain
  const float qscale = 0.17677669529663687f * 1.4426950408889634f;
#pragma unroll
  for (int ti=0;ti<2;ti++)
#pragma unroll
    for (int tj=0;tj<2;tj++)
#pragma unroll
      for (int r=0;r<4;r++){
        int n = mt*128 + w*32 + ti*16 + g*4 + r;
        int d = tj*16 + ln;
        float v = acc[ti][tj][r];
        if (set == 0){
          v = (v + bq[h*cDQ + d]) * qscale;
          qb[((size_t)h*cN + n)*cDQ + d] = f2bf(v);
        } else if (set == 1){
          v += bk[h*cDQ + d];
          kb[((size_t)h*cN + n)*cDQ + d] = f2bf(v);
        } else {
          v += bv[h*cDQ + d];
          vt[(size_t)h*cDQ*cN + (size_t)d*cN + n] = f2bf(v);
        }
      }
}

// ---------- K4: flash attention (R9 structure, KV-split x4, unroll 2) ----------
// Max-free softmax; shuffle-based P repack (proven); l cross-half hoisted out
// of the loop; #pragma unroll 2 so chunk i+1's loads/QK^T overlap chunk i's
// exp2/pack/PV in the scheduler.
__global__ __launch_bounds__(256) void k_attn(const u16* __restrict__ qb, const u16* __restrict__ kb,
    const u16* __restrict__ vt, float* __restrict__ opart, float* __restrict__ lpart){
  int bid = blockIdx.x;
  int h = bid & 7, s = (bid >> 3) & 3, qt = bid >> 5;
  int tid = threadIdx.x, w = tid >> 6, lane = tid & 63;
  int lq = lane & 31, hi = lane >> 5;
  int q0 = qt*128 + w*32;
  const u16* qh = qb + (size_t)h * cN * cDQ;
  const u16* kh = kb + (size_t)h * cN * cDQ;
  const u16* vh = vt + (size_t)h * cDQ * cN;
  short8 fq0 = *(const short8*)(qh + (size_t)(q0 + lq)*cDQ + hi*8);
  short8 fq1 = *(const short8*)(qh + (size_t)(q0 + lq)*cDQ + 16 + hi*8);
  f32x16 o;
#pragma unroll
  for (int r=0;r<16;r++) o[r] = 0.f;
  float l_loc = 0.f;
  const u16* vrow = vh + (size_t)lq * cN;
#pragma unroll 2
  for (int kc = 0; kc < 32; ++kc){
    int kbase = s*1024 + kc*32;
    short8 fk0 = *(const short8*)(kh + (size_t)(kbase + lq)*cDQ + hi*8);
    short8 fk1 = *(const short8*)(kh + (size_t)(kbase + lq)*cDQ + 16 + hi*8);
    f32x16 sa;
#pragma unroll
    for (int r=0;r<16;r++) sa[r] = 0.f;
    sa = __builtin_amdgcn_mfma_f32_32x32x16_bf16(fk0, fq0, sa, 0, 0, 0);
    sa = __builtin_amdgcn_mfma_f32_32x32x16_bf16(fk1, fq1, sa, 0, 0, 0);
    // p = exp2(S) directly (no max). In-lane sum; cross-half once after loop.
    float pf[16];
#pragma unroll
    for (int r=0;r<16;r++) pf[r] = __builtin_exp2f(sa[r]);
    float s01 = (pf[0]+pf[1]) + (pf[2]+pf[3]);
    float s23 = (pf[4]+pf[5]) + (pf[6]+pf[7]);
    float s45 = (pf[8]+pf[9]) + (pf[10]+pf[11]);
    float s67 = (pf[12]+pf[13]) + (pf[14]+pf[15]);
    l_loc += (s01 + s23) + (s45 + s67);
    // pack P -> bf16 B-operand fragment (shuffle-based, proven in R5-R9)
    u32 w0 = pktr(pf[0],  pf[1]),  w1 = pktr(pf[2],  pf[3]);
    u32 w2 = pktr(pf[4],  pf[5]),  w3 = pktr(pf[6],  pf[7]);
    u32 w4 = pktr(pf[8],  pf[9]),  w5 = pktr(pf[10], pf[11]);
    u32 w6 = pktr(pf[12], pf[13]), w7 = pktr(pf[14], pf[15]);
    u32 x0 = (u32)__shfl_xor((int)w0, 32), x1 = (u32)__shfl_xor((int)w1, 32);
    u32 x2 = (u32)__shfl_xor((int)w2, 32), x3 = (u32)__shfl_xor((int)w3, 32);
    u32 x4 = (u32)__shfl_xor((int)w4, 32), x5 = (u32)__shfl_xor((int)w5, 32);
    u32 x6 = (u32)__shfl_xor((int)w6, 32), x7 = (u32)__shfl_xor((int)w7, 32);
    union { u32x4 u; short8 s8; } pa1, pa2;
    pa1.u = u32x4{ hi ? x2 : w0, hi ? x3 : w1, hi ? w2 : x0, hi ? w3 : x1 };
    pa2.u = u32x4{ hi ? x6 : w4, hi ? x7 : w5, hi ? w6 : x4, hi ? w7 : x5 };
    short8 fv0 = *(const short8*)(vrow + kbase + hi*8);
    short8 fv1 = *(const short8*)(vrow + kbase + 16 + hi*8);
    // O^T[d][q] += V^T[d][k] * P[k][q]
    o = __builtin_amdgcn_mfma_f32_32x32x16_bf16(fv0, pa1.s8, o, 0, 0, 0);
    o = __builtin_amdgcn_mfma_f32_32x32x16_bf16(fv1, pa2.s8, o, 0, 0, 0);
  }
  float l_ = l_loc + __shfl_xor(l_loc, 32);
  // o[r] = O[q = q0+lq][d = (r&3)+8*(r>>2)+4*hi]
  size_t ob_base = ((size_t)(s*cH + h) * cN) * cDQ;
  float* orow = opart + ob_base + (size_t)(q0 + lq)*cDQ;
#pragma unroll
  for (int blk=0; blk<4; ++blk){
    f32x4 v4 = { o[blk*4+0], o[blk*4+1], o[blk*4+2], o[blk*4+3] };
    *(f32x4*)(orow + blk*8 + 4*hi) = v4;
  }
  if (lane < 32){
    lpart[(size_t)(s*cH + h) * cN + q0 + lane] = l_;
  }
}

// ---------- K4b: combine the 4 KV splits (max-free: weights all 1) ----------
__global__ __launch_bounds__(256) void k_comb(const float* __restrict__ opart,
    const float* __restrict__ lpart, u16* __restrict__ ob){
  int i = blockIdx.x * blockDim.x + threadIdx.x;   // over 8*4096*8
  int hq = i >> 3, dd = (i & 7) * 4;
  int h = hq >> 12, q = hq & 4095;
  float l = lpart[hq] + lpart[32768 + hq] + lpart[65536 + hq] + lpart[98304 + hq];
  float inv = 1.f / l;
  size_t base = (size_t)hq * cDQ + dd;
  float4 a = *(const float4*)(opart + base);
  float4 b = *(const float4*)(opart + 1048576 + base);
  float4 c = *(const float4*)(opart + 2097152 + base);
  float4 d = *(const float4*)(opart + 3145728 + base);
  u16* dst = ob + (size_t)q * (cH*cDQ) + h*cDQ + dd;
  dst[0] = f2bf((a.x+b.x+c.x+d.x)*inv); dst[1] = f2bf((a.y+b.y+c.y+d.y)*inv);
  dst[2] = f2bf((a.z+b.z+c.z+d.z)*inv); dst[3] = f2bf((a.w+b.w+c.w+d.w)*inv);
}

// ---------- K5: final projection o @ Wo + bo ----------
__global__ __launch_bounds__(256) void k_out(const u16* __restrict__ ob, const u16* __restrict__ wot,
    const float* __restrict__ bo, float* __restrict__ out){
  __shared__ __align__(16) u16 ldsA[8192], ldsB[8192];
  int mt = blockIdx.x;
  const u16* A = ob + (size_t)mt * 128 * 256;
  const u16* Bt = wot;
  int tid = threadIdx.x, wave = tid >> 6, lane = tid & 63;
  int wr = wave >> 1, wc = wave & 1, g = lane >> 4, ln = lane & 15;
  f32x4 acc[4][4];
#pragma unroll
  for (int i=0;i<4;i++)
#pragma unroll
    for (int j=0;j<4;j++) acc[i][j] = f32x4{0.f,0.f,0.f,0.f};
  for (int k0 = 0; k0 < 256; k0 += 64){
    stage_gl(A + k0, 256, ldsA, wave, lane);
    stage_gl(Bt + k0, 256, ldsB, wave, lane);
    __syncthreads();
    mma_tile(ldsA, ldsB, acc, wr, wc, g, ln);
    __syncthreads();
  }
#pragma unroll
  for (int ti=0;ti<4;ti++)
#pragma unroll
    for (int tj=0;tj<4;tj++)
#pragma unroll
      for (int r=0;r<4;r++){
        int n = mt*128 + wr*64 + ti*16 + g*4 + r;
        int f = wc*64 + tj*16 + ln;
        out[(size_t)n*cF + f] = acc[ti][tj][r] + bo[f];
      }
}

extern "C" void kernel_launch(void* const* d_in, const int* in_sizes, int n_in,
                              void* d_out, int out_size, void* d_ws, size_t ws_size,
                              hipStream_t stream){
  const float* adj  = (const float*)d_in[0];
  const float* x    = (const float*)d_in[1];
  const float* tvec = (const float*)d_in[2];
  // d_in[3] = PNum (unused)
  const float* Wself= (const float*)d_in[4];
  const float* bself= (const float*)d_in[5];
  const float* Wn   = (const float*)d_in[6];
  const float* bn   = (const float*)d_in[7];
  const float* Wc   = (const float*)d_in[8];
  const float* bc   = (const float*)d_in[9];
  const float* Wq   = (const float*)d_in[10];
  const float* bq   = (const float*)d_in[11];
  const float* Wk   = (const float*)d_in[12];
  const float* bk   = (const float*)d_in[13];
  const float* Wv   = (const float*)d_in[14];
  const float* bv   = (const float*)d_in[15];
  const float* Wo   = (const float*)d_in[16];
  const float* bo   = (const float*)d_in[17];
  float* out = (float*)d_out;

  char* ws = (char*)d_ws;
  u16* adjb = (u16*)(ws);              // 33,554,432 B (dead after k_ygemm)
  u16* xb   = (u16*)(ws + 33554432);   // 4096*256*2
  u16* xtT  = (u16*)(ws + 35651584);   // 256*4096*2 (x*t transposed)
  u16* w3t  = (u16*)(ws + 37748736);   // [3][8][128][256]*2 = 1,572,864
  u16* wqkvt= (u16*)(ws + 39321600);   // [3][8][32][128]*2 = 196,608
  u16* wot  = (u16*)(ws + 39518208);   // [128][256]*2 = 65,536
  u16* yb   = (u16*)(ws + 39583744);   // 4096*256*2
  u16* ybc  = (u16*)(ws + 41680896);   // 4096*256*2
  u16* hx   = (u16*)(ws + 43778048);   // [8][4096][128]*2 = 8,388,608
  u16* hn   = (u16*)(ws + 52166656);   // 8,388,608
  u16* hc   = (u16*)(ws + 60555264);   // 8,388,608
  u16* qb   = (u16*)(ws + 68943872);   // 2,097,152
  u16* kb   = (u16*)(ws + 71041024);   // 2,097,152
  u16* vt   = (u16*)(ws + 73138176);   // 2,097,152
  u16* ob   = (u16*)(ws + 75235328);   // 2,097,152  (total 77,332,480 B)
  // y partials alias hx..ob region (dead until k_ycomb finishes)
  float* ypart = (float*)(ws + 43778048);   // [8][4096][256] f32 = 33,554,432
  // attention partials alias adjb (dead after k_ygemm)
  float* opart = (float*)(ws);              // [4][8][4096][32] f32 = 16,777,216
  float* lpart = (float*)(ws + 16777216);   // [4][8][4096] f32 = 524,288

  k_conv8<<<8192, 256, 0, stream>>>(adj, adjb, 2097152);
  k_convx<<<4096, 256, 0, stream>>>(x, tvec, xb, xtT);
  k_tconv3<<<3072, 256, 0, stream>>>(Wself, Wn, Wc, w3t, 8, 256, 128);
  k_tconv3<<<384, 256, 0, stream>>>(Wq, Wk, Wv, wqkvt, 8, 128, 32);
  k_tconv<<<128, 256, 0, stream>>>(Wo, wot, 1, 256, 128);
  k_ygemm<<<512, 256, 0, stream>>>(adjb, xtT, ypart);
  k_ycomb<<<1024, 256, 0, stream>>>(ypart, x, tvec, yb, ybc);
  k_xw2<<<768, 256, 0, stream>>>(xb, yb, ybc, w3t, bself, bn, bc, hx, hn, hc);
  k_qkv<<<768, 256, 0, stream>>>(hx, hn, hc, wqkvt, bq, bk, bv, qb, kb, vt);
  k_attn<<<1024, 256, 0, stream>>>(qb, kb, vt, opart, lpart);
  k_comb<<<1024, 256, 0, stream>>>(opart, lpart, ob);
  k_out<<<32, 256, 0, stream>>>(ob, wot, bo, out);
}